// Round 10
// baseline (484.120 us; speedup 1.0000x reference)
//
#include <hip/hip_runtime.h>
#include <stdint.h>

#define NN 50000
#define NE 800000
#define CH 128

typedef double d4 __attribute__((ext_vector_type(4)));

// ---------------- threefry2x32 (exact JAX semantics) ----------------
__host__ __device__ inline void tf2x32(uint32_t k0, uint32_t k1, uint32_t& x0, uint32_t& x1) {
  uint32_t ks2 = k0 ^ k1 ^ 0x1BD11BDAu;
  x0 += k0; x1 += k1;
#define ROTL(v, r) (((v) << (r)) | ((v) >> (32 - (r))))
#define RND(r) { x0 += x1; x1 = ROTL(x1, r); x1 ^= x0; }
  RND(13) RND(15) RND(26) RND(6)
  x0 += k1; x1 += ks2 + 1u;
  RND(17) RND(29) RND(16) RND(24)
  x0 += ks2; x1 += k0 + 2u;
  RND(13) RND(15) RND(26) RND(6)
  x0 += k0; x1 += k1 + 3u;
  RND(17) RND(29) RND(16) RND(24)
  x0 += k1; x1 += ks2 + 4u;
  RND(13) RND(15) RND(26) RND(6)
  x0 += ks2; x1 += k0 + 5u;
#undef RND
#undef ROTL
}

__device__ inline float bits_to_u(uint32_t b) {
  float f = __uint_as_float(0x3F800000u | (b >> 9)) - 1.0f;  // [0,1)
  f = f + 1e-10f;
  return fmaxf(1e-10f, f);
}

// ---------------- graph preprocessing ----------------
__global__ __launch_bounds__(256) void deg_k(const int* __restrict__ dst, int* __restrict__ degi) {
  int i = blockIdx.x * 256 + threadIdx.x;
  if (i < NE) atomicAdd(&degi[dst[i]], 1);
}

// scan over degrees; also emits dinv
__global__ __launch_bounds__(256) void scan1_k(const int* __restrict__ degi, int* __restrict__ offs,
                                               int* __restrict__ part, float* __restrict__ dinv) {
  __shared__ int tmp[256];
  int t = threadIdx.x, b = blockIdx.x, i = b * 256 + t;
  int v = (i < NN) ? degi[i] : 0;
  tmp[t] = v;
  __syncthreads();
  for (int s = 1; s < 256; s <<= 1) {
    int a = (t >= s) ? tmp[t - s] : 0;
    __syncthreads();
    tmp[t] += a;
    __syncthreads();
  }
  int incl = tmp[t];
  if (i < NN) {
    offs[i] = incl - v;
    dinv[i] = 1.0f / sqrtf((float)(v + 1));
  }
  if (t == 255) part[b] = incl;
}

__global__ void scan2_k(int* part, int nparts) {
  if (threadIdx.x == 0 && blockIdx.x == 0) {
    int run = 0;
    for (int i = 0; i < nparts; ++i) { int v = part[i]; part[i] = run; run += v; }
  }
}

__global__ __launch_bounds__(256) void scan3_k(int* __restrict__ offs, const int* __restrict__ part) {
  int i = blockIdx.x * 256 + threadIdx.x;
  if (i < NN) offs[i] += part[blockIdx.x];
  if (i == 0) offs[NN] = NE;
}

// scatter edges into dst-buckets, writing src and norm directly.
// Intra-bucket order nondeterministic (atomic) — safe: downstream sums are f64.
__global__ __launch_bounds__(256) void place_k(const int* __restrict__ src, const int* __restrict__ dst,
                                               const int* __restrict__ offs, const float* __restrict__ dinv,
                                               int* __restrict__ cnt, int* __restrict__ srcs,
                                               float* __restrict__ norms) {
  int i = blockIdx.x * 256 + threadIdx.x;
  if (i < NE) {
    int d = dst[i], s = src[i];
    int p = offs[d] + atomicAdd(&cnt[d], 1);
    srcs[p] = s;
    norms[p] = dinv[s] * dinv[d];
  }
}

// ---------------- gumbel precompute (+ fused eout init to 3.0) ----------------
__global__ __launch_bounds__(256) void gum_k(float* __restrict__ gum, float* __restrict__ eout,
                                             uint32_t k00, uint32_t k01, uint32_t k10, uint32_t k11,
                                             uint32_t k20, uint32_t k21) {
  int i = blockIdx.x * 256 + threadIdx.x;
  if (i >= 3 * NN) return;
  if (i < NN) eout[i] = 3.0f;
  int l = i / NN;
  int n = i - l * NN;
  uint32_t kx, ky;
  if (l == 0) { kx = k00; ky = k01; }
  else if (l == 1) { kx = k10; ky = k11; }
  else { kx = k20; ky = k21; }
  int j0 = 2 * n, j1 = 2 * n + 1;
  uint32_t w0, w1;
  if (j0 < NN) {
    uint32_t a0 = (uint32_t)j0, a1 = (uint32_t)(j0 + NN);
    tf2x32(kx, ky, a0, a1); w0 = a0;
    uint32_t b0 = (uint32_t)j1, b1 = (uint32_t)(j1 + NN);
    tf2x32(kx, ky, b0, b1); w1 = b0;
  } else {
    uint32_t a0 = (uint32_t)(j0 - NN), a1 = (uint32_t)j0;
    tf2x32(kx, ky, a0, a1); w0 = a1;
    uint32_t b0 = (uint32_t)(j1 - NN), b1 = (uint32_t)j1;
    tf2x32(kx, ky, b0, b1); w1 = b1;
  }
  float u0 = bits_to_u(w0), u1 = bits_to_u(w1);
  gum[2 * (size_t)i]     = -logf(-logf(u0));
  gum[2 * (size_t)i + 1] = -logf(-logf(u1));
}

// ---------------- h = x @ W  (f32, 128x128 tile, BK=32, float4 both operands) ----------------
// k-order per output element strictly ascending -> bit-identical h. Node-major output.
__global__ __launch_bounds__(256) void lin_k(const float* __restrict__ x, const float* __restrict__ W,
                                             float* __restrict__ h) {
  __shared__ float Ws[32 * 128];    // [k][c]
  __shared__ float xs[128][36];     // [row][k], padded
  int t = threadIdx.x;
  int row0 = blockIdx.x << 7;
  int tr = t & 15, tc = t >> 4;     // rows tr+16i (i<8), col4s tc and 16+tc
  float4 acc[8][2];
#pragma unroll
  for (int i = 0; i < 8; ++i) { acc[i][0] = make_float4(0,0,0,0); acc[i][1] = make_float4(0,0,0,0); }

  for (int kt = 0; kt < 4; ++kt) {
    __syncthreads();
    {
      const float4* W4 = (const float4*)(W + (size_t)(kt * 32) * 128);
      float4* Ws4 = (float4*)Ws;
#pragma unroll
      for (int i = 0; i < 4; ++i) Ws4[t + 256 * i] = W4[t + 256 * i];
    }
    {
#pragma unroll
      for (int i = 0; i < 4; ++i) {
        int f = t + 256 * i;            // 0..1023
        int row = f >> 3, c4 = f & 7;
        int gr = row0 + row;
        float4 v = make_float4(0,0,0,0);
        if (gr < NN) v = ((const float4*)x)[(size_t)gr * 32 + kt * 8 + c4];
        *(float4*)&xs[row][4 * c4] = v;
      }
    }
    __syncthreads();
    const float4* Ws4 = (const float4*)Ws;
#pragma unroll
    for (int kk = 0; kk < 32; kk += 4) {
      float4 xv[8];
#pragma unroll
      for (int i = 0; i < 8; ++i) xv[i] = *(const float4*)&xs[tr + 16 * i][kk];
#pragma unroll
      for (int d = 0; d < 4; ++d) {
        float4 w0 = Ws4[(kk + d) * 32 + tc];
        float4 w1 = Ws4[(kk + d) * 32 + 16 + tc];
#pragma unroll
        for (int i = 0; i < 8; ++i) {
          float xd = ((const float*)&xv[i])[d];
          acc[i][0].x += xd * w0.x; acc[i][0].y += xd * w0.y;
          acc[i][0].z += xd * w0.z; acc[i][0].w += xd * w0.w;
          acc[i][1].x += xd * w1.x; acc[i][1].y += xd * w1.y;
          acc[i][1].z += xd * w1.z; acc[i][1].w += xd * w1.w;
        }
      }
    }
  }
#pragma unroll
  for (int i = 0; i < 8; ++i) {
    int gr = row0 + tr + 16 * i;
    if (gr < NN) {
      ((float4*)h)[(size_t)gr * 32 + tc] = acc[i][0];
      ((float4*)h)[(size_t)gr * 32 + 16 + tc] = acc[i][1];
    }
  }
}

// ---------------- sym-normalized aggregate + bias (+ GELU) ----------------
__device__ inline float gelu_exact(float v) {
  return 0.5f * v * (1.0f + erff(v / 1.4142135623730951f));
}

// wave per node; lanes 0-31 = even edge, 32-63 = odd edge; float4 per lane (4 ch).
// One VMEM instr fetches TWO h rows. (sum even + sum odd) + self, f64 -> safe.
__global__ __launch_bounds__(256) void agg_k(const float* __restrict__ h, const float* __restrict__ dinv,
                                             const int* __restrict__ offs, const int* __restrict__ srcs,
                                             const float* __restrict__ norms, const float* __restrict__ bias,
                                             float* __restrict__ xout, int act) {
  int lane = threadIdx.x & 63, w = threadIdx.x >> 6;
  int n = blockIdx.x * 4 + w;
  if (n >= NN) return;
  int c4 = lane & 31, hh = lane >> 5;
  int s0 = offs[n], s1 = offs[n + 1];
  double a0 = 0.0, a1 = 0.0, a2 = 0.0, a3 = 0.0;
  for (int p0 = s0; p0 < s1; p0 += 64) {
    int m = s1 - p0; if (m > 64) m = 64;
    int sv = 0; float nv = 0.f;
    if (lane < m) {
      sv = __builtin_nontemporal_load(&srcs[p0 + lane]);
      nv = __builtin_nontemporal_load(&norms[p0 + lane]);
    }
    int i = 0;
    for (; i + 8 <= m; i += 8) {
      int   sA = __shfl(sv, i + hh),     sB = __shfl(sv, i + 2 + hh);
      int   sC = __shfl(sv, i + 4 + hh), sD = __shfl(sv, i + 6 + hh);
      float nA = __shfl(nv, i + hh),     nB = __shfl(nv, i + 2 + hh);
      float nC = __shfl(nv, i + 4 + hh), nD = __shfl(nv, i + 6 + hh);
      float4 hA = *(const float4*)&h[(size_t)sA * CH + 4 * c4];
      float4 hB = *(const float4*)&h[(size_t)sB * CH + 4 * c4];
      float4 hC = *(const float4*)&h[(size_t)sC * CH + 4 * c4];
      float4 hD = *(const float4*)&h[(size_t)sD * CH + 4 * c4];
      a0 += (double)(hA.x * nA); a1 += (double)(hA.y * nA); a2 += (double)(hA.z * nA); a3 += (double)(hA.w * nA);
      a0 += (double)(hB.x * nB); a1 += (double)(hB.y * nB); a2 += (double)(hB.z * nB); a3 += (double)(hB.w * nB);
      a0 += (double)(hC.x * nC); a1 += (double)(hC.y * nC); a2 += (double)(hC.z * nC); a3 += (double)(hC.w * nC);
      a0 += (double)(hD.x * nD); a1 += (double)(hD.y * nD); a2 += (double)(hD.z * nD); a3 += (double)(hD.w * nD);
    }
    for (; i < m; i += 2) {
      int   s = __shfl(sv, i + hh);
      float nm = __shfl(nv, i + hh);
      float4 hv = *(const float4*)&h[(size_t)s * CH + 4 * c4];
      a0 += (double)(hv.x * nm); a1 += (double)(hv.y * nm); a2 += (double)(hv.z * nm); a3 += (double)(hv.w * nm);
    }
  }
  a0 += __shfl_xor(a0, 32); a1 += __shfl_xor(a1, 32);
  a2 += __shfl_xor(a2, 32); a3 += __shfl_xor(a3, 32);
  if (hh == 0) {
    float dv = dinv[n];
    float selfn = dv * dv;  // self-loop appended last, like ref
    float4 hn = *(const float4*)&h[(size_t)n * CH + 4 * c4];
    a0 += (double)(hn.x * selfn); a1 += (double)(hn.y * selfn);
    a2 += (double)(hn.z * selfn); a3 += (double)(hn.w * selfn);
    float4 bv = *(const float4*)&bias[4 * c4];
    float r0 = (float)a0 + bv.x;
    float r1 = (float)a1 + bv.y;
    float r2 = (float)a2 + bv.z;
    float r3 = (float)a3 + bv.w;
    if (act) { r0 = gelu_exact(r0); r1 = gelu_exact(r1); r2 = gelu_exact(r2); r3 = gelu_exact(r3); }
    float4 o; o.x = r0; o.y = r1; o.z = r2; o.w = r3;
    *(float4*)&xout[(size_t)n * CH + 4 * c4] = o;
  }
}

// ---------------- confidence MLP + gumbel decision via f64 MFMA ----------------
// W1 read from GLOBAL (L1-resident) -> LDS xs-only -> 4 blocks/CU.
// eout (init 3.0) is the state; no atomics. Verified numerics (r7/r9).
template <int MODE>
__global__ __launch_bounds__(256) void decide_k(const float* __restrict__ x, const float* __restrict__ W1,
                                                const float* __restrict__ b1, const float* __restrict__ W2,
                                                const float* __restrict__ b2, const float* __restrict__ gum,
                                                float* __restrict__ zout, float* __restrict__ eout,
                                                float layerf) {
  __shared__ float b1s[64];
  __shared__ float w2s[128];
  __shared__ float b2s[2];
  __shared__ float xs[4][16][132];
  int t = threadIdx.x;
  if (t < 64) b1s[t] = b1[t];
  if (t < 128) w2s[t] = W2[t];
  if (t < 2) b2s[t] = b2[t];

  int lane = t & 63, w = t >> 6;
  int n0 = blockIdx.x * 64 + w * 16;
#pragma unroll
  for (int i = 0; i < 8; ++i) {
    int f = lane + 64 * i;
    int row = f >> 5, c4 = f & 31;
    int gr = n0 + row;
    float4 v = make_float4(0.f, 0.f, 0.f, 0.f);
    if (gr < NN) v = ((const float4*)x)[(size_t)gr * 32 + c4];
    *(float4*)&xs[w][row][4 * c4] = v;
  }

  int g = lane >> 4, r = lane & 15;
  bool writer = (r < 4);
  int mynode = n0 + 4 * g + r;
  float ev = 3.0f;
  float gg0 = 0.f, gg1 = 0.f;
  if (writer && mynode < NN) {
    if (MODE > 0) ev = eout[mynode];
    gg0 = gum[2 * (size_t)mynode];
    gg1 = gum[2 * (size_t)mynode + 1];
  }
  bool m_act = writer && (mynode < NN) && (MODE == 0 || ev == 3.0f);
  unsigned long long actmask = __ballot(m_act);
  __syncthreads();
  if (MODE > 0 && actmask == 0ULL) return;

  d4 acc0 = {0., 0., 0., 0.}, acc1 = {0., 0., 0., 0.};
  d4 acc2 = {0., 0., 0., 0.}, acc3 = {0., 0., 0., 0.};
#pragma unroll 4
  for (int ks = 0; ks < 32; ++ks) {
    int k = 4 * ks + g;
    double av = (double)xs[w][r][k];
    const float* Wk = W1 + (size_t)k * 64;
    double b0 = (double)Wk[r];
    double b1v = (double)Wk[16 + r];
    double b2v = (double)Wk[32 + r];
    double b3v = (double)Wk[48 + r];
    acc0 = __builtin_amdgcn_mfma_f64_16x16x4f64(av, b0, acc0, 0, 0, 0);
    acc1 = __builtin_amdgcn_mfma_f64_16x16x4f64(av, b1v, acc1, 0, 0, 0);
    acc2 = __builtin_amdgcn_mfma_f64_16x16x4f64(av, b2v, acc2, 0, 0, 0);
    acc3 = __builtin_amdgcn_mfma_f64_16x16x4f64(av, b3v, acc3, 0, 0, 0);
  }

  double p0[4], p1[4];
#pragma unroll
  for (int i = 0; i < 4; ++i) {
    float h0 = fmaxf((float)acc0[i] + b1s[r], 0.f);
    float h1 = fmaxf((float)acc1[i] + b1s[16 + r], 0.f);
    float h2 = fmaxf((float)acc2[i] + b1s[32 + r], 0.f);
    float h3 = fmaxf((float)acc3[i] + b1s[48 + r], 0.f);
    double q0 = (double)h0 * (double)w2s[2 * r] + (double)h1 * (double)w2s[2 * (16 + r)] +
                (double)h2 * (double)w2s[2 * (32 + r)] + (double)h3 * (double)w2s[2 * (48 + r)];
    double q1 = (double)h0 * (double)w2s[2 * r + 1] + (double)h1 * (double)w2s[2 * (16 + r) + 1] +
                (double)h2 * (double)w2s[2 * (32 + r) + 1] + (double)h3 * (double)w2s[2 * (48 + r) + 1];
#pragma unroll
    for (int off = 1; off <= 8; off <<= 1) {
      q0 += __shfl_xor(q0, off);
      q1 += __shfl_xor(q1, off);
    }
    p0[i] = q0; p1[i] = q1;
  }

  double q0sel = p0[0], q1sel = p1[0];
  if (r == 1) { q0sel = p0[1]; q1sel = p1[1]; }
  if (r == 2) { q0sel = p0[2]; q1sel = p1[2]; }
  if (r == 3) { q0sel = p0[3]; q1sel = p1[3]; }
  bool myex = false;
  if (writer && mynode < NN) {
    float l0 = (float)q0sel + b2s[0];
    float l1 = (float)q1sel + b2s[1];
    myex = (l1 + gg1) > (l0 + gg0);
  }
  unsigned long long exmask = __ballot(myex);

  if (m_act && myex) eout[mynode] = layerf;

#pragma unroll
  for (int i = 0; i < 16; ++i) {
    int bitpos = 16 * (i >> 2) + (i & 3);
    bool a = (actmask >> bitpos) & 1ULL;
    bool ee = (exmask >> bitpos) & 1ULL;
    if (a && (MODE == 2 || ee)) {
      int node = n0 + i;
      float2 v;
      v.x = xs[w][i][2 * lane];
      v.y = xs[w][i][2 * lane + 1];
      *(float2*)&zout[(size_t)node * CH + 2 * lane] = v;
    }
  }
}

// single-block count of active[] from eout; no atomics
__global__ __launch_bounds__(1024) void cnt_k(const float* __restrict__ eout, float* __restrict__ aout) {
  __shared__ int s1[16], s2[16];
  int t = threadIdx.x;
  int c1 = 0, c2 = 0;
  for (int i = t; i < NN / 4; i += 1024) {
    float4 v = ((const float4*)eout)[i];
    c1 += (v.x < 0.5f) + (v.y < 0.5f) + (v.z < 0.5f) + (v.w < 0.5f);
    c2 += (v.x < 1.5f) + (v.y < 1.5f) + (v.z < 1.5f) + (v.w < 1.5f);
  }
#pragma unroll
  for (int off = 32; off >= 1; off >>= 1) { c1 += __shfl_xor(c1, off); c2 += __shfl_xor(c2, off); }
  if ((t & 63) == 0) { s1[t >> 6] = c1; s2[t >> 6] = c2; }
  __syncthreads();
  if (t == 0) {
    int a1 = 0, a2 = 0;
#pragma unroll
    for (int i = 0; i < 16; ++i) { a1 += s1[i]; a2 += s2[i]; }
    aout[0] = 50000.0f;
    aout[1] = (float)(NN - a1);
    aout[2] = (float)(NN - a2);
  }
}

// ---------------- host ----------------
extern "C" void kernel_launch(void* const* d_in, const int* in_sizes, int n_in,
                              void* d_out, int out_size, void* d_ws, size_t ws_size,
                              hipStream_t stream) {
  const float* x_in = (const float*)d_in[0];
  const int* eidx = (const int*)d_in[1];
  const int* esrc = eidx;
  const int* edst = eidx + NE;
  const float* convw[3] = {(const float*)d_in[2], (const float*)d_in[4], (const float*)d_in[6]};
  const float* convb[3] = {(const float*)d_in[3], (const float*)d_in[5], (const float*)d_in[7]};
  const float* cw1 = (const float*)d_in[8];
  const float* cb1 = (const float*)d_in[9];
  const float* cw2 = (const float*)d_in[10];
  const float* cb2 = (const float*)d_in[11];
  // d_in[12] = temp_w: unused (temperature > 0 cancels in the argmax)

  float* out = (float*)d_out;
  float* zout = out;
  float* eout = out + (size_t)NN * CH;
  float* aout = eout + NN;

  char* w = (char*)d_ws;
  float* P = (float*)w;   w += (size_t)NN * CH * 4;
  float* Q = (float*)w;   w += (size_t)NN * CH * 4;
  int* srcs = (int*)w;    w += (size_t)NE * 4;
  float* norms = (float*)w; w += (size_t)NE * 4;
  float* gum = (float*)w; w += (size_t)3 * NN * 2 * 4;
  int* offs = (int*)w;    w += (size_t)(NN + 1) * 4;
  float* dinv = (float*)w; w += (size_t)NN * 4;
  char* zr0 = w;
  int* degi = (int*)w;    w += (size_t)NN * 4;
  int* cnt = (int*)w;     w += (size_t)NN * 4;
  int* parts = (int*)w;   w += 1024;

  hipMemsetAsync(zr0, 0, (size_t)(2 * NN) * 4, stream);

  uint32_t key[3][2];
  for (int l = 0; l < 3; ++l) {
    uint32_t a = 0u, b = (uint32_t)l;
    tf2x32(0u, 42u, a, b);
    key[l][0] = a; key[l][1] = b;
  }

  const int nblkN = (NN + 255) / 256;
  deg_k<<<(NE + 255) / 256, 256, 0, stream>>>(edst, degi);
  scan1_k<<<nblkN, 256, 0, stream>>>(degi, offs, parts, dinv);
  scan2_k<<<1, 64, 0, stream>>>(parts, nblkN);
  scan3_k<<<nblkN, 256, 0, stream>>>(offs, parts);
  place_k<<<(NE + 255) / 256, 256, 0, stream>>>(esrc, edst, offs, dinv, cnt, srcs, norms);
  gum_k<<<(3 * NN + 255) / 256, 256, 0, stream>>>(gum, eout, key[0][0], key[0][1], key[1][0], key[1][1],
                                                  key[2][0], key[2][1]);

  const int LB = (NN + 127) / 128;  // 391 blocks
  const int AB = (NN + 3) / 4;      // 12500 blocks
  const int DB = (NN + 63) / 64;    // 782 blocks
  for (int l = 0; l < 3; ++l) {
    const float* xin = (l == 0) ? x_in : Q;
    lin_k<<<LB, 256, 0, stream>>>(xin, convw[l], P);
    agg_k<<<AB, 256, 0, stream>>>(P, dinv, offs, srcs, norms, convb[l], Q, (l < 2) ? 1 : 0);
    if (l == 0)
      decide_k<0><<<DB, 256, 0, stream>>>(Q, cw1, cb1, cw2, cb2, gum, zout, eout, 0.0f);
    else if (l == 1)
      decide_k<1><<<DB, 256, 0, stream>>>(Q, cw1, cb1, cw2, cb2, gum + (size_t)NN * 2, zout, eout, 1.0f);
    else
      decide_k<2><<<DB, 256, 0, stream>>>(Q, cw1, cb1, cw2, cb2, gum + (size_t)2 * NN * 2, zout, eout, 2.0f);
  }
  cnt_k<<<1, 1024, 0, stream>>>(eout, aout);
}

// Round 11
// 463.352 us; speedup vs baseline: 1.0448x; 1.0448x over previous
//
#include <hip/hip_runtime.h>
#include <stdint.h>

#define NN 50000
#define NE 800000
#define CH 128

typedef double d4 __attribute__((ext_vector_type(4)));

// ---------------- threefry2x32 (exact JAX semantics) ----------------
__host__ __device__ inline void tf2x32(uint32_t k0, uint32_t k1, uint32_t& x0, uint32_t& x1) {
  uint32_t ks2 = k0 ^ k1 ^ 0x1BD11BDAu;
  x0 += k0; x1 += k1;
#define ROTL(v, r) (((v) << (r)) | ((v) >> (32 - (r))))
#define RND(r) { x0 += x1; x1 = ROTL(x1, r); x1 ^= x0; }
  RND(13) RND(15) RND(26) RND(6)
  x0 += k1; x1 += ks2 + 1u;
  RND(17) RND(29) RND(16) RND(24)
  x0 += ks2; x1 += k0 + 2u;
  RND(13) RND(15) RND(26) RND(6)
  x0 += k0; x1 += k1 + 3u;
  RND(17) RND(29) RND(16) RND(24)
  x0 += k1; x1 += ks2 + 4u;
  RND(13) RND(15) RND(26) RND(6)
  x0 += ks2; x1 += k0 + 5u;
#undef RND
#undef ROTL
}

__device__ inline float bits_to_u(uint32_t b) {
  float f = __uint_as_float(0x3F800000u | (b >> 9)) - 1.0f;  // [0,1)
  f = f + 1e-10f;
  return fmaxf(1e-10f, f);
}

// ---------------- graph preprocessing ----------------
__global__ __launch_bounds__(256) void deg_k(const int* __restrict__ dst, int* __restrict__ degi) {
  int i = blockIdx.x * 256 + threadIdx.x;
  if (i < NE) atomicAdd(&degi[dst[i]], 1);
}

// scan over degrees; also emits dinv
__global__ __launch_bounds__(256) void scan1_k(const int* __restrict__ degi, int* __restrict__ offs,
                                               int* __restrict__ part, float* __restrict__ dinv) {
  __shared__ int tmp[256];
  int t = threadIdx.x, b = blockIdx.x, i = b * 256 + t;
  int v = (i < NN) ? degi[i] : 0;
  tmp[t] = v;
  __syncthreads();
  for (int s = 1; s < 256; s <<= 1) {
    int a = (t >= s) ? tmp[t - s] : 0;
    __syncthreads();
    tmp[t] += a;
    __syncthreads();
  }
  int incl = tmp[t];
  if (i < NN) {
    offs[i] = incl - v;
    dinv[i] = 1.0f / sqrtf((float)(v + 1));
  }
  if (t == 255) part[b] = incl;
}

__global__ void scan2_k(int* part, int nparts) {
  if (threadIdx.x == 0 && blockIdx.x == 0) {
    int run = 0;
    for (int i = 0; i < nparts; ++i) { int v = part[i]; part[i] = run; run += v; }
  }
}

__global__ __launch_bounds__(256) void scan3_k(int* __restrict__ offs, const int* __restrict__ part) {
  int i = blockIdx.x * 256 + threadIdx.x;
  if (i < NN) offs[i] += part[blockIdx.x];
  if (i == 0) offs[NN] = NE;
}

// scatter edges into dst-buckets; srcs only (norm computed on the fly in agg).
// Intra-bucket order nondeterministic (atomic) — safe: downstream sums are f64.
__global__ __launch_bounds__(256) void place_k(const int* __restrict__ src, const int* __restrict__ dst,
                                               const int* __restrict__ offs,
                                               int* __restrict__ cnt, int* __restrict__ srcs) {
  int i = blockIdx.x * 256 + threadIdx.x;
  if (i < NE) {
    int d = dst[i];
    int p = offs[d] + atomicAdd(&cnt[d], 1);
    srcs[p] = src[i];
  }
}

// ---------------- gumbel precompute (+ fused eout init to 3.0) ----------------
__global__ __launch_bounds__(256) void gum_k(float* __restrict__ gum, float* __restrict__ eout,
                                             uint32_t k00, uint32_t k01, uint32_t k10, uint32_t k11,
                                             uint32_t k20, uint32_t k21) {
  int i = blockIdx.x * 256 + threadIdx.x;
  if (i >= 3 * NN) return;
  if (i < NN) eout[i] = 3.0f;
  int l = i / NN;
  int n = i - l * NN;
  uint32_t kx, ky;
  if (l == 0) { kx = k00; ky = k01; }
  else if (l == 1) { kx = k10; ky = k11; }
  else { kx = k20; ky = k21; }
  int j0 = 2 * n, j1 = 2 * n + 1;
  uint32_t w0, w1;
  if (j0 < NN) {
    uint32_t a0 = (uint32_t)j0, a1 = (uint32_t)(j0 + NN);
    tf2x32(kx, ky, a0, a1); w0 = a0;
    uint32_t b0 = (uint32_t)j1, b1 = (uint32_t)(j1 + NN);
    tf2x32(kx, ky, b0, b1); w1 = b0;
  } else {
    uint32_t a0 = (uint32_t)(j0 - NN), a1 = (uint32_t)j0;
    tf2x32(kx, ky, a0, a1); w0 = a1;
    uint32_t b0 = (uint32_t)(j1 - NN), b1 = (uint32_t)j1;
    tf2x32(kx, ky, b0, b1); w1 = b1;
  }
  float u0 = bits_to_u(w0), u1 = bits_to_u(w1);
  gum[2 * (size_t)i]     = -logf(-logf(u0));
  gum[2 * (size_t)i + 1] = -logf(-logf(u1));
}

// ---------------- h = x @ W  (f32, 64x128 tile, BK=32, float4 both operands) ----------------
// k-order per output element strictly ascending -> bit-identical h. Node-major output.
__global__ __launch_bounds__(256) void lin_k(const float* __restrict__ x, const float* __restrict__ W,
                                             float* __restrict__ h) {
  __shared__ float Ws[32 * 128];    // [k][c]
  __shared__ float xs[64][36];      // [row][k], padded
  int t = threadIdx.x;
  int row0 = blockIdx.x << 6;
  int tr = t & 15, tc = t >> 4;     // rows tr+16i, col4s tc and 16+tc
  float4 acc[4][2];
#pragma unroll
  for (int i = 0; i < 4; ++i) { acc[i][0] = make_float4(0,0,0,0); acc[i][1] = make_float4(0,0,0,0); }

  for (int kt = 0; kt < 4; ++kt) {
    __syncthreads();
    {
      const float4* W4 = (const float4*)(W + (size_t)(kt * 32) * 128);
      float4* Ws4 = (float4*)Ws;
#pragma unroll
      for (int i = 0; i < 4; ++i) Ws4[t + 256 * i] = W4[t + 256 * i];
    }
    {
#pragma unroll
      for (int i = 0; i < 2; ++i) {
        int f = t + 256 * i;            // 0..511
        int row = f >> 3, c4 = f & 7;
        int gr = row0 + row;
        float4 v = make_float4(0,0,0,0);
        if (gr < NN) v = ((const float4*)x)[(size_t)gr * 32 + kt * 8 + c4];
        *(float4*)&xs[row][4 * c4] = v;
      }
    }
    __syncthreads();
    const float4* Ws4 = (const float4*)Ws;
#pragma unroll
    for (int kk = 0; kk < 32; kk += 4) {
      float4 xv[4];
#pragma unroll
      for (int i = 0; i < 4; ++i) xv[i] = *(const float4*)&xs[tr + 16 * i][kk];
#pragma unroll
      for (int d = 0; d < 4; ++d) {
        float4 w0 = Ws4[(kk + d) * 32 + tc];
        float4 w1 = Ws4[(kk + d) * 32 + 16 + tc];
#pragma unroll
        for (int i = 0; i < 4; ++i) {
          float xd = ((const float*)&xv[i])[d];
          acc[i][0].x += xd * w0.x; acc[i][0].y += xd * w0.y;
          acc[i][0].z += xd * w0.z; acc[i][0].w += xd * w0.w;
          acc[i][1].x += xd * w1.x; acc[i][1].y += xd * w1.y;
          acc[i][1].z += xd * w1.z; acc[i][1].w += xd * w1.w;
        }
      }
    }
  }
#pragma unroll
  for (int i = 0; i < 4; ++i) {
    int gr = row0 + tr + 16 * i;
    if (gr < NN) {
      ((float4*)h)[(size_t)gr * 32 + tc] = acc[i][0];
      ((float4*)h)[(size_t)gr * 32 + 16 + tc] = acc[i][1];
    }
  }
}

// ---------------- sym-normalized aggregate + bias (+ GELU) ----------------
__device__ inline float gelu_exact(float v) {
  return 0.5f * v * (1.0f + erff(v / 1.4142135623730951f));
}

// wave per node; lanes 0-31 = even edge, 32-63 = odd edge; float4 per lane (4 ch).
// norm computed on the fly: dinv[s]*dinv[n] f32 — bit-identical to precomputed.
__global__ __launch_bounds__(256) void agg_k(const float* __restrict__ h, const float* __restrict__ dinv,
                                             const int* __restrict__ offs, const int* __restrict__ srcs,
                                             const float* __restrict__ bias,
                                             float* __restrict__ xout, int act) {
  int lane = threadIdx.x & 63, w = threadIdx.x >> 6;
  int n = blockIdx.x * 4 + w;
  if (n >= NN) return;
  int c4 = lane & 31, hh = lane >> 5;
  int s0 = offs[n], s1 = offs[n + 1];
  float dv = dinv[n];
  double a0 = 0.0, a1 = 0.0, a2 = 0.0, a3 = 0.0;
  for (int p0 = s0; p0 < s1; p0 += 64) {
    int m = s1 - p0; if (m > 64) m = 64;
    int sv = 0; float nv = 0.f;
    if (lane < m) {
      sv = __builtin_nontemporal_load(&srcs[p0 + lane]);
      nv = dinv[sv] * dv;   // f32 product, identical to ref's norm
    }
    int i = 0;
    for (; i + 8 <= m; i += 8) {
      int   sA = __shfl(sv, i + hh),     sB = __shfl(sv, i + 2 + hh);
      int   sC = __shfl(sv, i + 4 + hh), sD = __shfl(sv, i + 6 + hh);
      float nA = __shfl(nv, i + hh),     nB = __shfl(nv, i + 2 + hh);
      float nC = __shfl(nv, i + 4 + hh), nD = __shfl(nv, i + 6 + hh);
      float4 hA = *(const float4*)&h[(size_t)sA * CH + 4 * c4];
      float4 hB = *(const float4*)&h[(size_t)sB * CH + 4 * c4];
      float4 hC = *(const float4*)&h[(size_t)sC * CH + 4 * c4];
      float4 hD = *(const float4*)&h[(size_t)sD * CH + 4 * c4];
      a0 += (double)(hA.x * nA); a1 += (double)(hA.y * nA); a2 += (double)(hA.z * nA); a3 += (double)(hA.w * nA);
      a0 += (double)(hB.x * nB); a1 += (double)(hB.y * nB); a2 += (double)(hB.z * nB); a3 += (double)(hB.w * nB);
      a0 += (double)(hC.x * nC); a1 += (double)(hC.y * nC); a2 += (double)(hC.z * nC); a3 += (double)(hC.w * nC);
      a0 += (double)(hD.x * nD); a1 += (double)(hD.y * nD); a2 += (double)(hD.z * nD); a3 += (double)(hD.w * nD);
    }
    for (; i < m; i += 2) {
      int   s = __shfl(sv, i + hh);
      float nm = __shfl(nv, i + hh);
      float4 hv = *(const float4*)&h[(size_t)s * CH + 4 * c4];
      a0 += (double)(hv.x * nm); a1 += (double)(hv.y * nm); a2 += (double)(hv.z * nm); a3 += (double)(hv.w * nm);
    }
  }
  a0 += __shfl_xor(a0, 32); a1 += __shfl_xor(a1, 32);
  a2 += __shfl_xor(a2, 32); a3 += __shfl_xor(a3, 32);
  if (hh == 0) {
    float selfn = dv * dv;  // self-loop appended last, like ref
    float4 hn = *(const float4*)&h[(size_t)n * CH + 4 * c4];
    a0 += (double)(hn.x * selfn); a1 += (double)(hn.y * selfn);
    a2 += (double)(hn.z * selfn); a3 += (double)(hn.w * selfn);
    float4 bv = *(const float4*)&bias[4 * c4];
    float r0 = (float)a0 + bv.x;
    float r1 = (float)a1 + bv.y;
    float r2 = (float)a2 + bv.z;
    float r3 = (float)a3 + bv.w;
    if (act) { r0 = gelu_exact(r0); r1 = gelu_exact(r1); r2 = gelu_exact(r2); r3 = gelu_exact(r3); }
    float4 o; o.x = r0; o.y = r1; o.z = r2; o.w = r3;
    *(float4*)&xout[(size_t)n * CH + 4 * c4] = o;
  }
}

// ---------------- confidence MLP + gumbel decision via f64 MFMA ----------------
// W1 read from GLOBAL (L1-resident) -> LDS xs-only -> 4 blocks/CU.
// eout (init 3.0) is the state; no atomics. Verified numerics (r7/r9).
template <int MODE>
__global__ __launch_bounds__(256) void decide_k(const float* __restrict__ x, const float* __restrict__ W1,
                                                const float* __restrict__ b1, const float* __restrict__ W2,
                                                const float* __restrict__ b2, const float* __restrict__ gum,
                                                float* __restrict__ zout, float* __restrict__ eout,
                                                float layerf) {
  __shared__ float b1s[64];
  __shared__ float w2s[128];
  __shared__ float b2s[2];
  __shared__ float xs[4][16][132];
  int t = threadIdx.x;
  if (t < 64) b1s[t] = b1[t];
  if (t < 128) w2s[t] = W2[t];
  if (t < 2) b2s[t] = b2[t];

  int lane = t & 63, w = t >> 6;
  int n0 = blockIdx.x * 64 + w * 16;
#pragma unroll
  for (int i = 0; i < 8; ++i) {
    int f = lane + 64 * i;
    int row = f >> 5, c4 = f & 31;
    int gr = n0 + row;
    float4 v = make_float4(0.f, 0.f, 0.f, 0.f);
    if (gr < NN) v = ((const float4*)x)[(size_t)gr * 32 + c4];
    *(float4*)&xs[w][row][4 * c4] = v;
  }

  int g = lane >> 4, r = lane & 15;
  bool writer = (r < 4);
  int mynode = n0 + 4 * g + r;
  float ev = 3.0f;
  float gg0 = 0.f, gg1 = 0.f;
  if (writer && mynode < NN) {
    if (MODE > 0) ev = eout[mynode];
    gg0 = gum[2 * (size_t)mynode];
    gg1 = gum[2 * (size_t)mynode + 1];
  }
  bool m_act = writer && (mynode < NN) && (MODE == 0 || ev == 3.0f);
  unsigned long long actmask = __ballot(m_act);
  __syncthreads();
  if (MODE > 0 && actmask == 0ULL) return;

  d4 acc0 = {0., 0., 0., 0.}, acc1 = {0., 0., 0., 0.};
  d4 acc2 = {0., 0., 0., 0.}, acc3 = {0., 0., 0., 0.};
#pragma unroll 4
  for (int ks = 0; ks < 32; ++ks) {
    int k = 4 * ks + g;
    double av = (double)xs[w][r][k];
    const float* Wk = W1 + (size_t)k * 64;
    double b0 = (double)Wk[r];
    double b1v = (double)Wk[16 + r];
    double b2v = (double)Wk[32 + r];
    double b3v = (double)Wk[48 + r];
    acc0 = __builtin_amdgcn_mfma_f64_16x16x4f64(av, b0, acc0, 0, 0, 0);
    acc1 = __builtin_amdgcn_mfma_f64_16x16x4f64(av, b1v, acc1, 0, 0, 0);
    acc2 = __builtin_amdgcn_mfma_f64_16x16x4f64(av, b2v, acc2, 0, 0, 0);
    acc3 = __builtin_amdgcn_mfma_f64_16x16x4f64(av, b3v, acc3, 0, 0, 0);
  }

  double p0[4], p1[4];
#pragma unroll
  for (int i = 0; i < 4; ++i) {
    float h0 = fmaxf((float)acc0[i] + b1s[r], 0.f);
    float h1 = fmaxf((float)acc1[i] + b1s[16 + r], 0.f);
    float h2 = fmaxf((float)acc2[i] + b1s[32 + r], 0.f);
    float h3 = fmaxf((float)acc3[i] + b1s[48 + r], 0.f);
    double q0 = (double)h0 * (double)w2s[2 * r] + (double)h1 * (double)w2s[2 * (16 + r)] +
                (double)h2 * (double)w2s[2 * (32 + r)] + (double)h3 * (double)w2s[2 * (48 + r)];
    double q1 = (double)h0 * (double)w2s[2 * r + 1] + (double)h1 * (double)w2s[2 * (16 + r) + 1] +
                (double)h2 * (double)w2s[2 * (32 + r) + 1] + (double)h3 * (double)w2s[2 * (48 + r) + 1];
#pragma unroll
    for (int off = 1; off <= 8; off <<= 1) {
      q0 += __shfl_xor(q0, off);
      q1 += __shfl_xor(q1, off);
    }
    p0[i] = q0; p1[i] = q1;
  }

  double q0sel = p0[0], q1sel = p1[0];
  if (r == 1) { q0sel = p0[1]; q1sel = p1[1]; }
  if (r == 2) { q0sel = p0[2]; q1sel = p1[2]; }
  if (r == 3) { q0sel = p0[3]; q1sel = p1[3]; }
  bool myex = false;
  if (writer && mynode < NN) {
    float l0 = (float)q0sel + b2s[0];
    float l1 = (float)q1sel + b2s[1];
    myex = (l1 + gg1) > (l0 + gg0);
  }
  unsigned long long exmask = __ballot(myex);

  if (m_act && myex) eout[mynode] = layerf;

#pragma unroll
  for (int i = 0; i < 16; ++i) {
    int bitpos = 16 * (i >> 2) + (i & 3);
    bool a = (actmask >> bitpos) & 1ULL;
    bool ee = (exmask >> bitpos) & 1ULL;
    if (a && (MODE == 2 || ee)) {
      int node = n0 + i;
      float2 v;
      v.x = xs[w][i][2 * lane];
      v.y = xs[w][i][2 * lane + 1];
      *(float2*)&zout[(size_t)node * CH + 2 * lane] = v;
    }
  }
}

// single-block count of active[] from eout; no atomics
__global__ __launch_bounds__(1024) void cnt_k(const float* __restrict__ eout, float* __restrict__ aout) {
  __shared__ int s1[16], s2[16];
  int t = threadIdx.x;
  int c1 = 0, c2 = 0;
  for (int i = t; i < NN / 4; i += 1024) {
    float4 v = ((const float4*)eout)[i];
    c1 += (v.x < 0.5f) + (v.y < 0.5f) + (v.z < 0.5f) + (v.w < 0.5f);
    c2 += (v.x < 1.5f) + (v.y < 1.5f) + (v.z < 1.5f) + (v.w < 1.5f);
  }
#pragma unroll
  for (int off = 32; off >= 1; off >>= 1) { c1 += __shfl_xor(c1, off); c2 += __shfl_xor(c2, off); }
  if ((t & 63) == 0) { s1[t >> 6] = c1; s2[t >> 6] = c2; }
  __syncthreads();
  if (t == 0) {
    int a1 = 0, a2 = 0;
#pragma unroll
    for (int i = 0; i < 16; ++i) { a1 += s1[i]; a2 += s2[i]; }
    aout[0] = 50000.0f;
    aout[1] = (float)(NN - a1);
    aout[2] = (float)(NN - a2);
  }
}

// ---------------- host ----------------
extern "C" void kernel_launch(void* const* d_in, const int* in_sizes, int n_in,
                              void* d_out, int out_size, void* d_ws, size_t ws_size,
                              hipStream_t stream) {
  const float* x_in = (const float*)d_in[0];
  const int* eidx = (const int*)d_in[1];
  const int* esrc = eidx;
  const int* edst = eidx + NE;
  const float* convw[3] = {(const float*)d_in[2], (const float*)d_in[4], (const float*)d_in[6]};
  const float* convb[3] = {(const float*)d_in[3], (const float*)d_in[5], (const float*)d_in[7]};
  const float* cw1 = (const float*)d_in[8];
  const float* cb1 = (const float*)d_in[9];
  const float* cw2 = (const float*)d_in[10];
  const float* cb2 = (const float*)d_in[11];
  // d_in[12] = temp_w: unused (temperature > 0 cancels in the argmax)

  float* out = (float*)d_out;
  float* zout = out;
  float* eout = out + (size_t)NN * CH;
  float* aout = eout + NN;

  char* w = (char*)d_ws;
  float* P = (float*)w;   w += (size_t)NN * CH * 4;
  float* Q = (float*)w;   w += (size_t)NN * CH * 4;
  int* srcs = (int*)w;    w += (size_t)NE * 4;
  float* gum = (float*)w; w += (size_t)3 * NN * 2 * 4;
  int* offs = (int*)w;    w += (size_t)(NN + 1) * 4;
  float* dinv = (float*)w; w += (size_t)NN * 4;
  char* zr0 = w;
  int* degi = (int*)w;    w += (size_t)NN * 4;
  int* cnt = (int*)w;     w += (size_t)NN * 4;
  int* parts = (int*)w;   w += 1024;

  hipMemsetAsync(zr0, 0, (size_t)(2 * NN) * 4, stream);

  uint32_t key[3][2];
  for (int l = 0; l < 3; ++l) {
    uint32_t a = 0u, b = (uint32_t)l;
    tf2x32(0u, 42u, a, b);
    key[l][0] = a; key[l][1] = b;
  }

  const int nblkN = (NN + 255) / 256;
  deg_k<<<(NE + 255) / 256, 256, 0, stream>>>(edst, degi);
  scan1_k<<<nblkN, 256, 0, stream>>>(degi, offs, parts, dinv);
  scan2_k<<<1, 64, 0, stream>>>(parts, nblkN);
  scan3_k<<<nblkN, 256, 0, stream>>>(offs, parts);
  place_k<<<(NE + 255) / 256, 256, 0, stream>>>(esrc, edst, offs, cnt, srcs);
  gum_k<<<(3 * NN + 255) / 256, 256, 0, stream>>>(gum, eout, key[0][0], key[0][1], key[1][0], key[1][1],
                                                  key[2][0], key[2][1]);

  const int LB = (NN + 63) / 64;   // 782 blocks
  const int AB = (NN + 3) / 4;     // 12500 blocks
  const int DB = (NN + 63) / 64;   // 782 blocks
  for (int l = 0; l < 3; ++l) {
    const float* xin = (l == 0) ? x_in : Q;
    lin_k<<<LB, 256, 0, stream>>>(xin, convw[l], P);
    agg_k<<<AB, 256, 0, stream>>>(P, dinv, offs, srcs, convb[l], Q, (l < 2) ? 1 : 0);
    if (l == 0)
      decide_k<0><<<DB, 256, 0, stream>>>(Q, cw1, cb1, cw2, cb2, gum, zout, eout, 0.0f);
    else if (l == 1)
      decide_k<1><<<DB, 256, 0, stream>>>(Q, cw1, cb1, cw2, cb2, gum + (size_t)NN * 2, zout, eout, 1.0f);
    else
      decide_k<2><<<DB, 256, 0, stream>>>(Q, cw1, cb1, cw2, cb2, gum + (size_t)2 * NN * 2, zout, eout, 2.0f);
  }
  cnt_k<<<1, 1024, 0, stream>>>(eout, aout);
}